// Round 6
// baseline (358.132 us; speedup 1.0000x reference)
//
#include <hip/hip_runtime.h>
#include <hip/hip_bf16.h>
#include <stdint.h>

// B=8, S=2048, D=512, H=2, hd=256. All dims hardcoded.
// 6 dispatches: f2b_all -> proj GEMM (merged rgb+event) -> gate
//   -> QKV GEMM (merged; Q*1/16*log2e compact, K natural [bh][seq][256],
//   V chunked) -> attn (split QK chains, XOR-swizzled K LDS, exp2 softmax)
//   -> final GEMM (mix fused in A-staging, +residual, f32)

typedef __bf16 bf16_t;
typedef __bf16 bf16x8 __attribute__((ext_vector_type(8)));
typedef float f32x4 __attribute__((ext_vector_type(4)));
typedef float f32x16 __attribute__((ext_vector_type(16)));
typedef unsigned int u32;

typedef void gvoid_t __attribute__((address_space(1)));
typedef void svoid_t __attribute__((address_space(3)));

__device__ inline void gload16(const void* g, void* l) {
    __builtin_amdgcn_global_load_lds((gvoid_t*)g, (svoid_t*)l, 16, 0, 0);
}

__device__ inline u32 cvtpk_bf16(float lo, float hi) {
    u32 r;
    asm("v_cvt_pk_bf16_f32 %0, %1, %2" : "=v"(r) : "v"(lo), "v"(hi));
    return r;
}

__device__ inline float exp2v(float x) {
    float r;
    asm("v_exp_f32 %0, %1" : "=v"(r) : "v"(x));
    return r;
}

// ---------------- all f32 -> bf16 converts in one dispatch ----------------
__global__ __launch_bounds__(256) void f2b_all(const float* __restrict__ s0, bf16_t* __restrict__ d0,
                                               const float* __restrict__ s1, bf16_t* __restrict__ d1,
                                               const float* __restrict__ s2, bf16_t* __restrict__ d2,
                                               const float* __restrict__ s3, bf16_t* __restrict__ d3,
                                               const float* __restrict__ s4, bf16_t* __restrict__ d4,
                                               const float* __restrict__ s5, bf16_t* __restrict__ d5) {
    int i = blockIdx.x * 256 + threadIdx.x;
    const float* s; bf16_t* d; int off;
    if (i < 1048576)      { s = s0; d = d0; off = i; }
    else if (i < 2097152) { s = s1; d = d1; off = i - 1048576; }
    else if (i < 2129920) { s = s2; d = d2; off = i - 2097152; }
    else if (i < 2162688) { s = s3; d = d3; off = i - 2129920; }
    else if (i < 2260992) { s = s4; d = d4; off = i - 2162688; }
    else                  { s = s5; d = d5; off = i - 2260992; }
    const float4* p = reinterpret_cast<const float4*>(s) + (size_t)off * 2;
    float4 a = p[0], b = p[1];
    bf16x8 o;
    o[0] = (bf16_t)a.x; o[1] = (bf16_t)a.y; o[2] = (bf16_t)a.z; o[3] = (bf16_t)a.w;
    o[4] = (bf16_t)b.x; o[5] = (bf16_t)b.y; o[6] = (bf16_t)b.z; o[7] = (bf16_t)b.w;
    reinterpret_cast<bf16x8*>(d)[off] = o;
}

// ---------------- GEMM: C = A @ B^T, 128x128 tile, BK=64, 4 waves ----------
// MODE 0 (proj, merged): blockIdx.y<128 -> (A,Bw,bias,C); else second set
// MODE 1 (QKV, merged): Q -> qdst[row][col]*(1/16*log2e);
//                       K -> kdst[bh][seq][256] natural;
//                       V -> vdst chunked [bh][kt][kc=(seq%32)/8][d][e=seq%8]
// MODE 2 (final): A-staging = gate-mix of A,A2; f32 out + residual
template <int MODE>
__global__ __launch_bounds__(256) void gemm_bt(const bf16_t* __restrict__ A,
                                               const bf16_t* __restrict__ A2,
                                               const bf16_t* __restrict__ Bw,
                                               const bf16_t* __restrict__ Bw2,
                                               const float* __restrict__ bias,
                                               const float* __restrict__ bias2,
                                               void* __restrict__ Cout,
                                               void* __restrict__ Cout2,
                                               const bf16_t* __restrict__ r1,
                                               const bf16_t* __restrict__ r2,
                                               const float* __restrict__ gate,
                                               bf16_t* __restrict__ qdst,
                                               bf16_t* __restrict__ kdst,
                                               bf16_t* __restrict__ vdst,
                                               bf16_t* __restrict__ qdst2,
                                               bf16_t* __restrict__ kdst2,
                                               bf16_t* __restrict__ vdst2,
                                               int N, int K) {
    __shared__ __align__(16) bf16_t As[128][64];
    __shared__ __align__(16) bf16_t Bs[128][64];
    const int tid = threadIdx.x, lane = tid & 63, w = tid >> 6;
    const int l16 = lane & 15, l4 = lane >> 4;
    const int wm = w >> 1, wn = w & 1;
    const bool sec = (MODE != 2) && (blockIdx.y >= 128);
    const size_t a0 = (size_t)(blockIdx.y & 127) * 128;
    const size_t b0 = (size_t)blockIdx.x * 128;
    const bf16_t* Ap = sec ? A2 : A;
    const bf16_t* Bp = sec ? Bw2 : Bw;
    const float* bp = sec ? bias2 : bias;
    f32x4 acc[4][4] = {};
    const int srow = w * 32 + (lane >> 3);
    const int scol = (lane & 7) * 8;
    float g4[4];
    if (MODE == 2) {
#pragma unroll
        for (int i = 0; i < 4; ++i) g4[i] = gate[a0 + srow + i * 8];
    }
    for (int kt = 0; kt < K; kt += 64) {
        __syncthreads();
        if (MODE == 2) {
#pragma unroll
            for (int i = 0; i < 4; ++i) {
                size_t ro = (a0 + srow + i * 8) * (size_t)K + kt + scol;
                bf16x8 x = *reinterpret_cast<const bf16x8*>(A + ro);
                bf16x8 y = *reinterpret_cast<const bf16x8*>(A2 + ro);
                bf16x8 o;
#pragma unroll
                for (int j = 0; j < 8; ++j)
                    o[j] = (bf16_t)(g4[i] * (float)x[j] + (1.f - g4[i]) * (float)y[j]);
                *reinterpret_cast<bf16x8*>(&As[srow + i * 8][scol]) = o;
            }
        } else {
#pragma unroll
            for (int i = 0; i < 4; ++i)
                gload16(Ap + (a0 + srow + i * 8) * (size_t)K + kt + scol, &As[w * 32 + i * 8][0]);
        }
#pragma unroll
        for (int i = 0; i < 4; ++i)
            gload16(Bp + (b0 + srow + i * 8) * (size_t)K + kt + scol, &Bs[w * 32 + i * 8][0]);
        __syncthreads();
#pragma unroll
        for (int kk = 0; kk < 2; ++kk) {
            bf16x8 af[4], bfr[4];
#pragma unroll
            for (int mi = 0; mi < 4; ++mi)
                af[mi] = *reinterpret_cast<const bf16x8*>(&As[wm * 64 + mi * 16 + l16][kk * 32 + l4 * 8]);
#pragma unroll
            for (int ni = 0; ni < 4; ++ni)
                bfr[ni] = *reinterpret_cast<const bf16x8*>(&Bs[wn * 64 + ni * 16 + l16][kk * 32 + l4 * 8]);
#pragma unroll
            for (int mi = 0; mi < 4; ++mi)
#pragma unroll
                for (int ni = 0; ni < 4; ++ni)
                    acc[mi][ni] = __builtin_amdgcn_mfma_f32_16x16x32_bf16(af[mi], bfr[ni], acc[mi][ni], 0, 0, 0);
        }
    }
    bf16_t* qd = sec ? qdst2 : qdst;
    bf16_t* kd = sec ? kdst2 : kdst;
    bf16_t* vd = sec ? vdst2 : vdst;
#pragma unroll
    for (int mi = 0; mi < 4; ++mi) {
#pragma unroll
        for (int ni = 0; ni < 4; ++ni) {
            int col = (int)b0 + wn * 64 + ni * 16 + l16;
            float bs = bp[col];
            int row0 = (int)a0 + wm * 64 + mi * 16 + l4 * 4;
            float vv[4];
#pragma unroll
            for (int r = 0; r < 4; ++r) vv[r] = acc[mi][ni][r] + bs;
            if (MODE == 0) {
                bf16_t* Cp = (bf16_t*)(sec ? Cout2 : Cout);
#pragma unroll
                for (int r = 0; r < 4; ++r)
                    Cp[(size_t)(row0 + r) * N + col] = (bf16_t)vv[r];
            } else if (MODE == 2) {
#pragma unroll
                for (int r = 0; r < 4; ++r) {
                    size_t idx = (size_t)(row0 + r) * N + col;
                    ((float*)Cout)[idx] = vv[r] + 0.5f * ((float)r1[idx] + (float)r2[idx]);
                }
            } else {
                if (col < 512) {
#pragma unroll
                    for (int r = 0; r < 4; ++r)
                        qd[(size_t)(row0 + r) * 512 + col] = (bf16_t)(vv[r] * 0.090168440f);
                } else if (col < 1024) {
                    int cc = col - 512, h = cc >> 8, d = cc & 255;
#pragma unroll
                    for (int r = 0; r < 4; ++r) {
                        int row = row0 + r;
                        int bh = (row >> 11) * 2 + h, seq = row & 2047;
                        kd[(size_t)bh * 524288 + (size_t)seq * 256 + d] = (bf16_t)vv[r];
                    }
                } else {
                    int cc = col - 1024, h = cc >> 8, d = cc & 255;
                    int bh = (row0 >> 11) * 2 + h, seq = row0 & 2047;
                    size_t idx = ((size_t)(bh * 64 + (seq >> 5))) * 8192 +
                                 ((seq >> 3) & 3) * 2048 + d * 8 + (seq & 7);
                    union { bf16_t h4[4]; uint2 u8; } pk;
#pragma unroll
                    for (int r = 0; r < 4; ++r) pk.h4[r] = (bf16_t)vv[r];
                    *reinterpret_cast<uint2*>(&vd[idx]) = pk.u8;
                }
            }
        }
    }
}

// ---------------- gate = sigmoid(sum(rgb_p*event_p, axis=-1)) ----------------
__global__ __launch_bounds__(256) void gate_kernel(const bf16_t* __restrict__ rp,
                                                   const bf16_t* __restrict__ ep,
                                                   float* __restrict__ gate) {
    int row = blockIdx.x * 4 + (threadIdx.x >> 6);
    int lane = threadIdx.x & 63;
    bf16x8 a = reinterpret_cast<const bf16x8*>(rp + (size_t)row * 512)[lane];
    bf16x8 b = reinterpret_cast<const bf16x8*>(ep + (size_t)row * 512)[lane];
    float s = 0.f;
#pragma unroll
    for (int j = 0; j < 8; ++j) s += (float)a[j] * (float)b[j];
#pragma unroll
    for (int off = 32; off; off >>= 1) s += __shfl_xor(s, off, 64);
    if (lane == 0) gate[row] = 1.f / (1.f + __expf(-s));
}

// ---------------- flash attention ----------------
// grid 512: bid = qb*32 + dir*16 + bh. 4 waves, wave owns 32 q rows, KVBLK=32.
// K natural [bh][seq][256] staged with XOR source pre-swizzle (G21), reads
// XOR'd -> conflict-free. V chunked (linear). Split QK chains (2x8-deep),
// tree softmax reductions, exp2 domain, defer-max.
__global__ __launch_bounds__(256, 2) void attn_kernel(const bf16_t* __restrict__ qbr,
                                                      const bf16_t* __restrict__ qbe,
                                                      const bf16_t* __restrict__ kbr,
                                                      const bf16_t* __restrict__ kbe,
                                                      const bf16_t* __restrict__ vbr,
                                                      const bf16_t* __restrict__ vbe,
                                                      bf16_t* __restrict__ out0,
                                                      bf16_t* __restrict__ out1) {
    __shared__ __align__(16) bf16_t smem[32768];  // K[2][8192] | V[2][8192]
    const int bid = blockIdx.x;
    const int qb = bid >> 5;
    const int combo = bid & 31;
    const int dir = combo >> 4;
    const int bh = combo & 15;
    const int b = bh >> 1, h = bh & 1;
    const bf16_t* Qb = dir ? qbe : qbr;
    const bf16_t* Kc = dir ? kbr : kbe;
    const bf16_t* Vc = dir ? vbr : vbe;
    bf16_t* osrc = dir ? out1 : out0;
    const int tid = threadIdx.x;
    const int w = tid >> 6, l = tid & 63;
    const int l31 = l & 31, hi = l >> 5;
    const int q0w = qb * 128 + w * 32;

    const bf16_t* qp = Qb + ((size_t)(b * 2048 + q0w + l31)) * 512 + h * 256 + hi * 8;
    bf16x8 qf[16];
#pragma unroll
    for (int dch = 0; dch < 16; ++dch)
        qf[dch] = *reinterpret_cast<const bf16x8*>(qp + dch * 16);

    f32x16 O[8] = {};
    float mrun = -1e30f, lrun = 0.f;
    union PA { u32 uw[4]; bf16x8 v; } pa0, pa1;

    // K staging: natural layout, source pre-swizzled (chunk c_src = l31 ^ r)
    const bf16_t* kq = Kc + (size_t)bh * 524288;
    u32 koff[4];
#pragma unroll
    for (int i = 0; i < 4; ++i) {
        int r = w * 8 + i * 2 + hi;
        koff[i] = (u32)(r * 256 + ((l31 ^ r) * 8));
    }
    const bf16_t* vq = Vc + (size_t)bh * 524288 + (w * 2048 + l * 8);

#define STAGE(T, P)                                                        \
    do {                                                                   \
        const bf16_t* kt_ = kq + (size_t)(T) * 8192;                       \
        const bf16_t* vs_ = vq + (size_t)(T) * 8192;                       \
        bf16_t* lv_ = &smem[16384 + (P) * 8192 + w * 2048];                \
        gload16(kt_ + koff[0], &smem[(P) * 8192 + (w * 8 + 0) * 256]);     \
        gload16(kt_ + koff[1], &smem[(P) * 8192 + (w * 8 + 2) * 256]);     \
        gload16(kt_ + koff[2], &smem[(P) * 8192 + (w * 8 + 4) * 256]);     \
        gload16(kt_ + koff[3], &smem[(P) * 8192 + (w * 8 + 6) * 256]);     \
        gload16(vs_, lv_); gload16(vs_ + 512, lv_ + 512);                  \
        gload16(vs_ + 1024, lv_ + 1024); gload16(vs_ + 1536, lv_ + 1536);  \
    } while (0)

    STAGE(0, 0);

    for (int kt2 = 0; kt2 < 64; ++kt2) {
        asm volatile("s_waitcnt vmcnt(0)" ::: "memory");
        __builtin_amdgcn_s_barrier();
        if (kt2 < 63) STAGE(kt2 + 1, (kt2 + 1) & 1);

        const int cb = kt2 & 1;
        const bf16_t* kb = &smem[cb * 8192 + l31 * 256];
        const bf16_t* vb = &smem[16384 + cb * 8192 + hi * 2048 + l31 * 8];

        // QK^T (swapped, split into two independent 8-deep chains)
        f32x16 st0 = {}, st1 = {};
        __builtin_amdgcn_s_setprio(1);
#pragma unroll
        for (int dp = 0; dp < 8; ++dp) {
            bf16x8 k0 = *reinterpret_cast<const bf16x8*>(kb + (((2 * dp) * 2 + hi) ^ l31) * 8);
            st0 = __builtin_amdgcn_mfma_f32_32x32x16_bf16(k0, qf[2 * dp], st0, 0, 0, 0);
            bf16x8 k1 = *reinterpret_cast<const bf16x8*>(kb + (((2 * dp + 1) * 2 + hi) ^ l31) * 8);
            st1 = __builtin_amdgcn_mfma_f32_32x32x16_bf16(k1, qf[2 * dp + 1], st1, 0, 0, 0);
        }
        __builtin_amdgcn_s_setprio(0);
        f32x16 st = st0 + st1;

        // online softmax (lane-local, q=l31), tree reductions
        float mx4[4];
#pragma unroll
        for (int j = 0; j < 4; ++j)
            mx4[j] = fmaxf(fmaxf(st[4 * j], st[4 * j + 1]), fmaxf(st[4 * j + 2], st[4 * j + 3]));
        float mx = fmaxf(fmaxf(mx4[0], mx4[1]), fmaxf(mx4[2], mx4[3]));
        mx = fmaxf(mx, __shfl_xor(mx, 32, 64));
        if (__any(mx - mrun > 8.f)) {
            float mnew = fmaxf(mrun, mx);
            float sc = exp2v(mrun - mnew);
            mrun = mnew;
            lrun *= sc;
#pragma unroll
            for (int r = 0; r < 16; ++r) {
                int qr = (r & 3) + 8 * (r >> 2) + 4 * hi;
                float scr = __shfl(sc, qr, 64);
#pragma unroll
                for (int g = 0; g < 8; ++g) O[g][r] *= scr;
            }
        }
        float p_[16];
#pragma unroll
        for (int r = 0; r < 16; ++r) p_[r] = exp2v(st[r] - mrun);
        u32 W[8];
#pragma unroll
        for (int m = 0; m < 8; ++m) W[m] = cvtpk_bf16(p_[2 * m], p_[2 * m + 1]);
        float s4[4];
#pragma unroll
        for (int j = 0; j < 4; ++j)
            s4[j] = (p_[4 * j] + p_[4 * j + 1]) + (p_[4 * j + 2] + p_[4 * j + 3]);
        float lsum = (s4[0] + s4[1]) + (s4[2] + s4[3]);
        lsum += __shfl_xor(lsum, 32, 64);
        lrun += lsum;
        {
            u32 t0 = hi ? W[0] : W[2], t1 = hi ? W[1] : W[3];
            u32 r0 = (u32)__shfl_xor((int)t0, 32, 64);
            u32 r1 = (u32)__shfl_xor((int)t1, 32, 64);
            pa0.uw[0] = hi ? r0 : W[0]; pa0.uw[1] = hi ? r1 : W[1];
            pa0.uw[2] = hi ? W[2] : r0; pa0.uw[3] = hi ? W[3] : r1;
        }
        {
            u32 t0 = hi ? W[4] : W[6], t1 = hi ? W[5] : W[7];
            u32 r0 = (u32)__shfl_xor((int)t0, 32, 64);
            u32 r1 = (u32)__shfl_xor((int)t1, 32, 64);
            pa1.uw[0] = hi ? r0 : W[4]; pa1.uw[1] = hi ? r1 : W[5];
            pa1.uw[2] = hi ? W[6] : r0; pa1.uw[3] = hi ? W[7] : r1;
        }

        // PV (independent O[g] targets)
        __builtin_amdgcn_s_setprio(1);
#pragma unroll
        for (int g = 0; g < 8; ++g) {
            bf16x8 v0 = *reinterpret_cast<const bf16x8*>(vb + g * 256);
            O[g] = __builtin_amdgcn_mfma_f32_32x32x16_bf16(pa0.v, v0, O[g], 0, 0, 0);
        }
#pragma unroll
        for (int g = 0; g < 8; ++g) {
            bf16x8 v1 = *reinterpret_cast<const bf16x8*>(vb + 4096 + g * 256);
            O[g] = __builtin_amdgcn_mfma_f32_32x32x16_bf16(pa1.v, v1, O[g], 0, 0, 0);
        }
        __builtin_amdgcn_s_setprio(0);
    }
#undef STAGE

    // normalize (lrun broadcast per q-row) and store
#pragma unroll
    for (int r = 0; r < 16; ++r) {
        int qr = (r & 3) + 8 * (r >> 2) + 4 * hi;
        float linv = 1.0f / __shfl(lrun, qr, 64);
        size_t rowoff = ((size_t)(b * 2048 + q0w + qr)) * 512 + h * 256 + l31;
#pragma unroll
        for (int g = 0; g < 8; ++g)
            osrc[rowoff + g * 32] = (bf16_t)(O[g][r] * linv);
    }
}

extern "C" void kernel_launch(void* const* d_in, const int* in_sizes, int n_in,
                              void* d_out, int out_size, void* d_ws, size_t ws_size,
                              hipStream_t stream) {
    const float* rgb = (const float*)d_in[0];
    const float* event = (const float*)d_in[1];
    const float* w_rgb = (const float*)d_in[2];
    const float* b_rgb = (const float*)d_in[3];
    const float* w_event = (const float*)d_in[4];
    const float* b_event = (const float*)d_in[5];
    const float* w_in = (const float*)d_in[6];
    const float* b_in = (const float*)d_in[7];
    const float* w_out = (const float*)d_in[8];
    const float* b_out = (const float*)d_in[9];
    float* out = (float*)d_out;

    const size_t MB16 = (size_t)16 * 1024 * 1024;
    char* ws = (char*)d_ws;
    bf16_t* wrgb_bf = (bf16_t*)(ws + 0);
    bf16_t* wevt_bf = (bf16_t*)(ws + 524288);
    bf16_t* wout_bf = (bf16_t*)(ws + 1048576);
    bf16_t* win_bf = (bf16_t*)(ws + 1572864);
    float* gate = (float*)(ws + 3145728);
    bf16_t* bufA = (bf16_t*)(ws + 4194304);            // rgb bf16 -> attn out dir0
    bf16_t* bufB = (bf16_t*)(ws + 4194304 + MB16);     // event bf16 -> attn out dir1
    bf16_t* rgbp = (bf16_t*)(ws + 4194304 + 2 * MB16);
    bf16_t* evtp = (bf16_t*)(ws + 4194304 + 3 * MB16);
    bf16_t* qbr  = (bf16_t*)(ws + 4194304 + 4 * MB16);
    bf16_t* qbe  = (bf16_t*)(ws + 4194304 + 5 * MB16);
    bf16_t* kbr  = (bf16_t*)(ws + 4194304 + 6 * MB16);
    bf16_t* kbe  = (bf16_t*)(ws + 4194304 + 7 * MB16);
    bf16_t* vbr  = (bf16_t*)(ws + 4194304 + 8 * MB16);
    bf16_t* vbe  = (bf16_t*)(ws + 4194304 + 9 * MB16);

    dim3 blk(256);
    f2b_all<<<8960, blk, 0, stream>>>(rgb, bufA, event, bufB, w_rgb, wrgb_bf,
                                      w_event, wevt_bf, w_in, win_bf, w_out, wout_bf);
    gemm_bt<0><<<dim3(4, 256), blk, 0, stream>>>(bufA, bufB, wrgb_bf, wevt_bf, b_rgb, b_event,
                                                 rgbp, evtp, nullptr, nullptr, nullptr,
                                                 nullptr, nullptr, nullptr, nullptr, nullptr,
                                                 nullptr, 512, 512);
    gate_kernel<<<4096, blk, 0, stream>>>(rgbp, evtp, gate);
    gemm_bt<1><<<dim3(12, 256), blk, 0, stream>>>(rgbp, evtp, win_bf, win_bf, b_in, b_in,
                                                  nullptr, nullptr, nullptr, nullptr, nullptr,
                                                  qbr, kbr, vbr, qbe, kbe, vbe, 1536, 512);
    attn_kernel<<<512, blk, 0, stream>>>(qbr, qbe, kbr, kbe, vbr, vbe, bufA, bufB);
    gemm_bt<2><<<dim3(4, 128), blk, 0, stream>>>(bufA, bufB, wout_bf, nullptr, b_out, nullptr,
                                                 out, nullptr, rgbp, evtp, gate,
                                                 nullptr, nullptr, nullptr, nullptr, nullptr,
                                                 nullptr, 512, 512);
}